// Round 9
// baseline (296.253 us; speedup 1.0000x reference)
//
#include <hip/hip_runtime.h>
#include <math.h>

// SparseGate: B=16384, D=2048, E=64, k=2
// R9 "fusedE": vmcnt-FIFO decoupling. R3-R8 invariant: every structure ~80 us,
// all pipes <20%. Shared mechanism: per-kt B-register loads share the FIFO
// vmcnt with long-latency x prefetches -> each B-consume drains x-loads
// (oldest-first) -> every kt serializes on HBM latency.
// Fix: (1) x staged by global_load_lds DMA (fp32, width16, linear dest,
// inverse-swizzled source, XOR on read - rule 21); (2) B bulk-preloaded per
// phase into ping-pong regs -> compute phase has ZERO vmem consumption; the
// only drain is the end-of-phase barrier, issued a full phase early.
// Geometry/fragments/3-pass numerics/reduce/gate: verbatim R5 (verified).
#define NROWS 16384
#define DDIM  2048
#define NEXP  64
#define NCOL  128            // fused: 64 gate cols + 64 noise cols

constexpr float TAU = 1e-3f;        // margin below which we recheck in fp32

typedef __attribute__((ext_vector_type(8))) short short8;
typedef __attribute__((ext_vector_type(4))) float floatx4;

#define AS1 __attribute__((address_space(1)))
#define AS3 __attribute__((address_space(3)))

// async global->LDS DMA, 16 B per lane: lds dest = uniform base + lane*16
__device__ __forceinline__ void dma16(const float* g, float* l)
{
    __builtin_amdgcn_global_load_lds((const AS1 void*)g, (AS3 void*)l, 16, 0, 0);
}

// ---------------- fp32 -> bf16 hi/lo truncation split ----------------
__device__ __forceinline__ void split8(const float4 a, const float4 b,
                                       short8* hi, short8* lo)
{
    float f[8] = {a.x, a.y, a.z, a.w, b.x, b.y, b.z, b.w};
    union { unsigned short u[8]; short8 v; } H, L;
    #pragma unroll
    for (int j = 0; j < 8; ++j) {
        const unsigned int u  = __float_as_uint(f[j]);
        const unsigned int hf = u & 0xFFFF0000u;
        const float lf = f[j] - __uint_as_float(hf);   // exact
        H.u[j] = (unsigned short)(u >> 16);
        L.u[j] = (unsigned short)(__float_as_uint(lf) >> 16);
    }
    *hi = H.v; *lo = L.v;
}

__device__ __forceinline__ float softplus_f(float x) {
    return fmaxf(x, 0.f) + log1pf(expf(-fabsf(x)));
}

// ---------------- top-k + softmax over a 64-lane row ----------------
__device__ __forceinline__ float row_gate(int lane, float ew, int k, float* margin)
{
    float cur = ew;
    const float myv = ew;
    float m0 = 0.f, denom = 0.f, vk = 0.f, vk1 = 0.f;
    int selected = 0;
    const int iters = (k < NEXP) ? (k + 1) : k;
    for (int t = 0; t < iters; ++t) {
        float v = cur;
        int idx = lane;
        #pragma unroll
        for (int off = 32; off; off >>= 1) {
            const float ov = __shfl_xor(v, off);
            const int   oi = __shfl_xor(idx, off);
            if (ov > v || (ov == v && oi < idx)) { v = ov; idx = oi; }
        }
        if (t == 0) m0 = v;
        if (t < k) {
            denom += expf(v - m0);
            vk = v;
            if (lane == idx) { selected = 1; cur = -INFINITY; }
        } else {
            vk1 = v;
        }
    }
    *margin = (k < NEXP) ? (vk - vk1) : 1e30f;
    return selected ? expf(myv - m0) / denom : 0.f;
}

// ---------------- weight prep: pack B in exact wave-read order ----------------
// UNCHANGED (verified). Bpk short index:
//   (((kt*8 + ct)*2 + h)*64 + ln)*8 + j   (1 MB total)
// value = bf16 part h of W[col = ct*16 + (ln&15)][k = kt*32 + (ln>>4)*8 + j]
__global__ __launch_bounds__(256) void wprep_kernel(
    const float* __restrict__ gw, const float* __restrict__ nw,
    unsigned short* __restrict__ bpk, int* __restrict__ counter)
{
    const int g = blockIdx.x * 256 + threadIdx.x;    // 0..32767
    if (g == 0) counter[0] = 0;
    const int kt = g >> 9;            // 0..63
    const int ct = (g >> 6) & 7;      // 0..7
    const int ln = g & 63;            // 0..63
    const int col = ct * 16 + (ln & 15);
    const int kb  = kt * 32 + (ln >> 4) * 8;
    const float* src = (col < NEXP) ? (gw + (size_t)col * DDIM)
                                    : (nw + (size_t)(col - NEXP) * DDIM);
    src += kb;
    const float4 a = *(const float4*)src;
    const float4 b = *(const float4*)(src + 4);
    short8 hi, lo;
    split8(a, b, &hi, &lo);
    const size_t base = ((size_t)(kt * 8 + ct) * 2) * 512 + (size_t)ln * 8;
    *(short8*)&bpk[base]       = hi;    // h=0
    *(short8*)&bpk[base + 512] = lo;    // h=1
}

// ---------------- fused in-block-split-K GEMM + gate, DMA staging ---------
// Block = 64 rows x 128 cols x K=2048, 1024 thr = 16 waves = 4 kg x 4 wv.
// Wave tile (R5): 32 rows x 64 cols; per kt: 24 MFMA. 16 phases of 32-k/kg.
// Per phase: [bulk B(kt+1) 8 loads | sched_barrier | 2x dma16 x(kt+1) |
// sched_barrier] -> compute (LDS reads + cvt + MFMA, NO vmem) -> barrier
// (drains DMA+B issued a full phase earlier -> cheap).
// x LDS tile per kg = 64 r x 32 k fp32; row = 8 units of 16 B; unit at
// position p = u ^ (row&7) (XOR swizzle; inverse applied on DMA source).
__global__ __launch_bounds__(1024, 4) void fusedE_kernel(
    const float* __restrict__ x,
    const unsigned short* __restrict__ bpk,
    const float* __restrict__ noise,
    const int* __restrict__ kptr,
    float* __restrict__ out,
    int* __restrict__ counter,
    int* __restrict__ list)
{
    __shared__ __align__(16) float xb[2][4][64 * 32];   // 64 KB: [buf][kg][r*32+f]
    __shared__ float ew[64][NCOL];                      // 32 KB

    const int tid  = threadIdx.x;
    const int wid  = tid >> 6;          // 0..15
    const int kg   = wid >> 2;          // K-quarter 0..3
    const int wv   = wid & 3;           // wave within kg (R5 role)
    const int ln   = tid & 63;
    const int l15  = ln & 15;
    const int quad = ln >> 4;

    const int rowbase = blockIdx.x * 64;         // grid.x = 256

    // wave tile (verbatim R5)
    const int rh     = (wv >> 1) * 32;           // row half
    const int ctbase = (wv & 1) * 4;             // col quarter base (4 ct's)

    // ---- DMA source addressing (per lane) ----
    // wave stages local rows wv*16 .. wv*16+15 of its kg tile, 2 instrs:
    // instr i: rows wv*16+i*8 .. +7; lane l -> row +(l>>3), 16B-unit (l&7).
    // inverse swizzle: global unit u = (l&7) ^ ((l>>3)&7).
    const int rA = wv * 16 + (ln >> 3);          // i=0 local row
    const int uu = (ln & 7) ^ ((ln >> 3) & 7);
    const float* gb0 = x + (size_t)(rowbase + rA) * DDIM + kg * 512 + uu * 4;
    const float* gb1 = gb0 + (size_t)8 * DDIM;   // i=1: rows +8, same u

    // ---- fragment read addressing (per lane, constant across phases) ----
    const int sr = l15 & 7;
    const int p0 = (2 * quad) ^ sr;              // 16B-unit of floats q*8..+3
    const int p1 = p0 ^ 1;                       // floats q*8+4..+7
    const int fb0 = (rh + l15) * 32;             // rt=0 row base (floats)
    const int fb1 = (rh + 16 + l15) * 32;        // rt=1 row base

    const short8* bp = (const short8*)bpk;       // idx = ((kt*8+ct)*2+h)*64 + ln
    const int kt0 = kg * 16;                     // this kg's first 32-k slice

    floatx4 acc[2][4];
    #pragma unroll
    for (int rt = 0; rt < 2; ++rt)
        #pragma unroll
        for (int ct = 0; ct < 4; ++ct)
            acc[rt][ct] = (floatx4){0.f, 0.f, 0.f, 0.f};

    short8 bA[4][2], bB[4][2];                   // ping-pong bulk B

    // ---- prologue: B(kt=0) + DMA tile(kt=0) into buf 0 ----
    #pragma unroll
    for (int ct = 0; ct < 4; ++ct) {
        bA[ct][0] = bp[(size_t)((kt0 * 8 + ctbase + ct) * 2 + 0) * 64 + ln];
        bA[ct][1] = bp[(size_t)((kt0 * 8 + ctbase + ct) * 2 + 1) * 64 + ln];
    }
    __builtin_amdgcn_sched_barrier(0);
    dma16(gb0, &xb[0][kg][(wv * 16) * 32]);
    dma16(gb1, &xb[0][kg][(wv * 16 + 8) * 32]);
    __builtin_amdgcn_sched_barrier(0);
    __syncthreads();    // drains prologue DMA + B

    // one phase: issue B(kt+1)+DMA(kt+1) early, compute kt (no vmem), barrier
    #define PHASE(kt, BUF, bc, bn)                                             \
    {                                                                          \
        if ((kt) + 1 < 16) {                                                   \
            const int ktn = kt0 + (kt) + 1;                                    \
            _Pragma("unroll")                                                  \
            for (int ct = 0; ct < 4; ++ct) {                                   \
                bn[ct][0] = bp[(size_t)((ktn * 8 + ctbase + ct) * 2 + 0) * 64 + ln]; \
                bn[ct][1] = bp[(size_t)((ktn * 8 + ctbase + ct) * 2 + 1) * 64 + ln]; \
            }                                                                  \
            __builtin_amdgcn_sched_barrier(0);                                 \
            dma16(gb0 + ((kt) + 1) * 32, &xb[BUF ^ 1][kg][(wv * 16) * 32]);    \
            dma16(gb1 + ((kt) + 1) * 32, &xb[BUF ^ 1][kg][(wv * 16 + 8) * 32]);\
            __builtin_amdgcn_sched_barrier(0);                                 \
        }                                                                      \
        short8 ahi[2], alo[2];                                                 \
        {                                                                      \
            const float4 f0 = *(const float4*)&xb[BUF][kg][fb0 + p0 * 4];      \
            const float4 f1 = *(const float4*)&xb[BUF][kg][fb0 + p1 * 4];      \
            split8(f0, f1, &ahi[0], &alo[0]);                                  \
            const float4 g0 = *(const float4*)&xb[BUF][kg][fb1 + p0 * 4];      \
            const float4 g1 = *(const float4*)&xb[BUF][kg][fb1 + p1 * 4];      \
            split8(g0, g1, &ahi[1], &alo[1]);                                  \
        }                                                                      \
        _Pragma("unroll")                                                      \
        for (int ct = 0; ct < 4; ++ct) {                                       \
            const short8 bh = bc[ct][0];                                       \
            const short8 bl = bc[ct][1];                                       \
            acc[0][ct] = __builtin_amdgcn_mfma_f32_16x16x32_bf16(ahi[0], bh, acc[0][ct], 0, 0, 0); \
            acc[1][ct] = __builtin_amdgcn_mfma_f32_16x16x32_bf16(ahi[1], bh, acc[1][ct], 0, 0, 0); \
            acc[0][ct] = __builtin_amdgcn_mfma_f32_16x16x32_bf16(ahi[0], bl, acc[0][ct], 0, 0, 0); \
            acc[1][ct] = __builtin_amdgcn_mfma_f32_16x16x32_bf16(ahi[1], bl, acc[1][ct], 0, 0, 0); \
            acc[0][ct] = __builtin_amdgcn_mfma_f32_16x16x32_bf16(alo[0], bh, acc[0][ct], 0, 0, 0); \
            acc[1][ct] = __builtin_amdgcn_mfma_f32_16x16x32_bf16(alo[1], bh, acc[1][ct], 0, 0, 0); \
        }                                                                      \
        __syncthreads();                                                       \
    }

    #pragma unroll
    for (int m = 0; m < 8; ++m) {
        PHASE(2 * m,     0, bA, bB)
        PHASE(2 * m + 1, 1, bB, bA)
    }
    #undef PHASE

    // ---- phased partial reduce into ew (C/D: col=l15, row=quad*4+reg) ----
    #pragma unroll
    for (int p = 0; p < 4; ++p) {
        if (kg == p) {
            #pragma unroll
            for (int rt = 0; rt < 2; ++rt)
                #pragma unroll
                for (int r = 0; r < 4; ++r) {
                    const int row = rh + rt * 16 + quad * 4 + r;
                    float* rowp = &ew[row][(wv & 1) * 64 + l15];
                    #pragma unroll
                    for (int ct = 0; ct < 4; ++ct) {
                        if (p == 0) rowp[ct * 16]  = acc[rt][ct][r];
                        else        rowp[ct * 16] += acc[rt][ct][r];
                    }
                }
        }
        __syncthreads();
    }

    // ---- gate: 16 waves x 4 rows each ----
    int k = kptr[0];
    if (k < 1) k = 1;
    if (k > NEXP) k = NEXP;

    #pragma unroll
    for (int rr = 0; rr < 4; ++rr) {
        const int row  = wid * 4 + rr;
        const int grow = rowbase + row;
        const float clean = ew[row][ln];
        const float noisy = ew[row][NEXP + ln];
        const float nz    = noise[(size_t)grow * NEXP + ln];
        const float ewv   = clean + nz * softplus_f(noisy);
        float margin;
        const float val = row_gate(ln, ewv, k, &margin);
        out[(size_t)grow * NEXP + ln] = val;
        if (margin < TAU && ln == 0) {
            const int pos = atomicAdd(counter, 1);
            list[pos] = grow;
        }
    }
}

// ---------------- exact fp32 recheck for low-margin rows ----------------
__global__ __launch_bounds__(256) void recheck_kernel(
    const float* __restrict__ x,
    const float* __restrict__ gw,
    const float* __restrict__ nw,
    const float* __restrict__ noise,
    const int* __restrict__ kptr,
    float* __restrict__ out,
    const int* __restrict__ counter,
    const int* __restrict__ list)
{
    __shared__ float xr[DDIM];      // 8 KB
    __shared__ float parts[256];
    __shared__ float lg[NCOL];

    const int tid = threadIdx.x;
    const int cnt = counter[0];

    int k = kptr[0];
    if (k < 1) k = 1;
    if (k > NEXP) k = NEXP;

    for (int ii = blockIdx.x; ii < cnt; ii += gridDim.x) {
        const int row = list[ii];
        const float4* xs = (const float4*)(x + (size_t)row * DDIM);
        #pragma unroll
        for (int j = 0; j < 2; ++j)
            ((float4*)xr)[tid + j * 256] = xs[tid + j * 256];
        __syncthreads();

        const int e = tid & 127;
        const int half = tid >> 7;
        const float* wc = (e < NEXP) ? (gw + (size_t)e * DDIM)
                                     : (nw + (size_t)(e - NEXP) * DDIM);
        wc += half * 1024;
        const float* xc = xr + half * 1024;
        float s = 0.f;
        #pragma unroll 4
        for (int j = 0; j < 1024; j += 4) {
            float4 w4 = *(const float4*)&wc[j];
            s += xc[j] * w4.x + xc[j + 1] * w4.y + xc[j + 2] * w4.z + xc[j + 3] * w4.w;
        }
        parts[tid] = s;
        __syncthreads();
        if (tid < NCOL) lg[tid] = parts[tid] + parts[tid + 128];
        __syncthreads();
        if (tid < NEXP) {
            const float ew = lg[tid] + noise[(size_t)row * NEXP + tid] * softplus_f(lg[NEXP + tid]);
            float margin;
            const float val = row_gate(tid, ew, k, &margin);
            out[(size_t)row * NEXP + tid] = val;
        }
        __syncthreads();
    }
}

// ---------------- fallback: exact per-row (only if ws too small) ----------------
__global__ __launch_bounds__(256) void naive_kernel(
    const float* __restrict__ x,
    const float* __restrict__ gw,
    const float* __restrict__ nw,
    const float* __restrict__ noise,
    const int* __restrict__ kptr,
    float* __restrict__ out)
{
    const int lane = threadIdx.x & 63;
    const int wave = threadIdx.x >> 6;
    const int row  = blockIdx.x * 4 + wave;
    if (row >= NROWS) return;

    int k = kptr[0];
    if (k < 1) k = 1;
    if (k > NEXP) k = NEXP;

    const float* xr = x  + (size_t)row  * DDIM;
    const float* g  = gw + (size_t)lane * DDIM;
    const float* w2 = nw + (size_t)lane * DDIM;
    float c = 0.f, n = 0.f;
    for (int d = 0; d < DDIM; ++d) {
        const float xv = xr[d];
        c += xv * g[d];
        n += xv * w2[d];
    }
    const float ew = c + noise[(size_t)row * NEXP + lane] * softplus_f(n);
    float margin;
    out[(size_t)row * NEXP + lane] = row_gate(lane, ew, k, &margin);
}

// ---------------------------------------------------------------------------
extern "C" void kernel_launch(void* const* d_in, const int* in_sizes, int n_in,
                              void* d_out, int out_size, void* d_ws, size_t ws_size,
                              hipStream_t stream)
{
    const float* x     = (const float*)d_in[0];
    const float* gw    = (const float*)d_in[1];
    const float* nw    = (const float*)d_in[2];
    const float* noise = (const float*)d_in[3];
    const int*   kptr  = (const int*)d_in[4];
    float* out = (float*)d_out;

    // ws: bpk (1 MB) | counter (256 B) | list (64 KB)
    const size_t BPK_BYTES = (size_t)NCOL * DDIM * 2 * sizeof(unsigned short); // 1 MB
    const size_t TAIL      = 256 + NROWS * sizeof(int);

    if (ws_size < BPK_BYTES + TAIL) {
        hipLaunchKernelGGL(naive_kernel, dim3(NROWS / 4), dim3(256), 0, stream,
                           x, gw, nw, noise, kptr, out);
        return;
    }

    unsigned short* bpk     = (unsigned short*)d_ws;
    int*            counter = (int*)((char*)d_ws + BPK_BYTES);
    int*            list    = counter + 64;

    hipLaunchKernelGGL(wprep_kernel, dim3(128), dim3(256), 0, stream,
                       gw, nw, bpk, counter);
    hipLaunchKernelGGL(fusedE_kernel, dim3(NROWS / 64), dim3(1024), 0, stream,
                       x, bpk, noise, kptr, out, counter, list);
    hipLaunchKernelGGL(recheck_kernel, dim3(256), dim3(256), 0, stream,
                       x, gw, nw, noise, kptr, out, counter, list);
}

// Round 10
// 269.489 us; speedup vs baseline: 1.0993x; 1.0993x over previous
//
#include <hip/hip_runtime.h>
#include <math.h>

// SparseGate: B=16384, D=2048, E=64, k=2
// R10 "fusedE2": R9's vmcnt-FIFO decoupling WITHOUT the spill.
// R9 autopsy: FETCH 72->106 MB, WRITE 4->126 MB = scratch spill; demand
// (acc32 + B-pingpong64 + frags16 + addr) hit the hard 128-reg cap of
// 1024-thr blocks. Fix: wave = 32r x 32c (16 waves = 2 kg x 8 wv) ->
// B ping-pong 32 regs, acc 16; est ~98 regs, 30 slack.
// Per phase: [B(kt+1) 4 loads + 1 dma16 x(kt+1)] -> compute kt (NO vmem)
// -> barrier (drains loads issued a full phase earlier -> cheap).
// x staged by global_load_lds (linear dest, inverse-swz source, XOR read -
// R9-verified addressing). wprep/numerics/gate/recheck byte-identical.
#define NROWS 16384
#define DDIM  2048
#define NEXP  64
#define NCOL  128            // fused: 64 gate cols + 64 noise cols

constexpr float TAU = 1e-3f;        // margin below which we recheck in fp32

typedef __attribute__((ext_vector_type(8))) short short8;
typedef __attribute__((ext_vector_type(4))) float floatx4;

#define AS1 __attribute__((address_space(1)))
#define AS3 __attribute__((address_space(3)))

// async global->LDS DMA, 16 B per lane: lds dest = uniform base + lane*16
__device__ __forceinline__ void dma16(const float* g, float* l)
{
    __builtin_amdgcn_global_load_lds((const AS1 void*)g, (AS3 void*)l, 16, 0, 0);
}

// ---------------- fp32 -> bf16 hi/lo truncation split ----------------
__device__ __forceinline__ void split8(const float4 a, const float4 b,
                                       short8* hi, short8* lo)
{
    float f[8] = {a.x, a.y, a.z, a.w, b.x, b.y, b.z, b.w};
    union { unsigned short u[8]; short8 v; } H, L;
    #pragma unroll
    for (int j = 0; j < 8; ++j) {
        const unsigned int u  = __float_as_uint(f[j]);
        const unsigned int hf = u & 0xFFFF0000u;
        const float lf = f[j] - __uint_as_float(hf);   // exact
        H.u[j] = (unsigned short)(u >> 16);
        L.u[j] = (unsigned short)(__float_as_uint(lf) >> 16);
    }
    *hi = H.v; *lo = L.v;
}

__device__ __forceinline__ float softplus_f(float x) {
    return fmaxf(x, 0.f) + log1pf(expf(-fabsf(x)));
}

// ---------------- top-k + softmax over a 64-lane row ----------------
__device__ __forceinline__ float row_gate(int lane, float ew, int k, float* margin)
{
    float cur = ew;
    const float myv = ew;
    float m0 = 0.f, denom = 0.f, vk = 0.f, vk1 = 0.f;
    int selected = 0;
    const int iters = (k < NEXP) ? (k + 1) : k;
    for (int t = 0; t < iters; ++t) {
        float v = cur;
        int idx = lane;
        #pragma unroll
        for (int off = 32; off; off >>= 1) {
            const float ov = __shfl_xor(v, off);
            const int   oi = __shfl_xor(idx, off);
            if (ov > v || (ov == v && oi < idx)) { v = ov; idx = oi; }
        }
        if (t == 0) m0 = v;
        if (t < k) {
            denom += expf(v - m0);
            vk = v;
            if (lane == idx) { selected = 1; cur = -INFINITY; }
        } else {
            vk1 = v;
        }
    }
    *margin = (k < NEXP) ? (vk - vk1) : 1e30f;
    return selected ? expf(myv - m0) / denom : 0.f;
}

// ---------------- weight prep: pack B in exact wave-read order ----------------
// UNCHANGED (verified). Bpk short index:
//   (((kt*8 + ct)*2 + h)*64 + ln)*8 + j   (1 MB total)
// value = bf16 part h of W[col = ct*16 + (ln&15)][k = kt*32 + (ln>>4)*8 + j]
__global__ __launch_bounds__(256) void wprep_kernel(
    const float* __restrict__ gw, const float* __restrict__ nw,
    unsigned short* __restrict__ bpk, int* __restrict__ counter)
{
    const int g = blockIdx.x * 256 + threadIdx.x;    // 0..32767
    if (g == 0) counter[0] = 0;
    const int kt = g >> 9;            // 0..63
    const int ct = (g >> 6) & 7;      // 0..7
    const int ln = g & 63;            // 0..63
    const int col = ct * 16 + (ln & 15);
    const int kb  = kt * 32 + (ln >> 4) * 8;
    const float* src = (col < NEXP) ? (gw + (size_t)col * DDIM)
                                    : (nw + (size_t)(col - NEXP) * DDIM);
    src += kb;
    const float4 a = *(const float4*)src;
    const float4 b = *(const float4*)(src + 4);
    short8 hi, lo;
    split8(a, b, &hi, &lo);
    const size_t base = ((size_t)(kt * 8 + ct) * 2) * 512 + (size_t)ln * 8;
    *(short8*)&bpk[base]       = hi;    // h=0
    *(short8*)&bpk[base + 512] = lo;    // h=1
}

// ---------------- fused in-block-split-K GEMM + gate, DMA staging ---------
// Block = 64 rows x 128 cols x K=2048, 1024 thr = 16 waves = 2 kg x 8 wv.
// Wave tile: 32 rows x 32 cols (rh = (wv>>2)*32, ct0 = (wv&3)*2);
// per kt: 12 MFMA (2 rt x 2 ct x 3 passes). 32 phases of 32-k per kg.
// x LDS tile per kg/buf = 64 r x 32 k fp32 (8 KB); row = 8 units of 16 B,
// swizzled: LDS unit u holds global unit u^(r&7) (inverse on DMA source).
// Stage: wave wv DMAs local rows wv*8..+7 in ONE dma16 (lane l -> row l>>3,
// unit l&7, source unit (l&7)^((l>>3)&7)).
__global__ __launch_bounds__(1024, 4) void fusedE2_kernel(
    const float* __restrict__ x,
    const unsigned short* __restrict__ bpk,
    const float* __restrict__ noise,
    const int* __restrict__ kptr,
    float* __restrict__ out,
    int* __restrict__ counter,
    int* __restrict__ list)
{
    __shared__ __align__(16) float xb[2][2][64 * 32];   // 32 KB: [buf][kg][r*32+f]
    __shared__ float ew[64][132];                       // 33,792 B (pad: 4-way->spread)

    const int tid  = threadIdx.x;
    const int wid  = tid >> 6;          // 0..15
    const int kg   = wid >> 3;          // K-half 0..1
    const int wv   = wid & 7;           // wave within kg
    const int ln   = tid & 63;
    const int l15  = ln & 15;
    const int quad = ln >> 4;

    const int rowbase = blockIdx.x * 64;         // grid.x = 256

    // wave tile
    const int rh  = (wv >> 2) * 32;              // row half
    const int ct0 = (wv & 3) * 2;                // first col-16 tile

    // ---- DMA addressing: wave stages local rows wv*8..+7, one dma16 ----
    const int rA = wv * 8 + (ln >> 3);
    const int uu = (ln & 7) ^ ((ln >> 3) & 7);   // inverse swizzle on source
    const float* gb = x + (size_t)(rowbase + rA) * DDIM + kg * 1024 + uu * 4;
    float* ldst0 = &xb[0][kg][(wv * 8) * 32];    // wave-uniform dest, buf 0
    float* ldst1 = &xb[1][kg][(wv * 8) * 32];    // buf 1

    // ---- fragment read addressing (constant across phases) ----
    const int sr  = l15 & 7;
    const int p0  = (2 * quad) ^ sr;             // LDS unit of floats q*8..+3
    const int p1  = p0 ^ 1;                      // floats q*8+4..+7
    const int fb0 = (rh + l15) * 32;             // rt=0 row base (floats)
    const int fb1 = (rh + 16 + l15) * 32;        // rt=1 row base

    const short8* bp = (const short8*)bpk;       // idx = ((kt*8+ct)*2+h)*64 + ln
    const int kt0 = kg * 32;                     // this kg's first 32-k slice

    floatx4 acc[2][2];
    #pragma unroll
    for (int rt = 0; rt < 2; ++rt)
        #pragma unroll
        for (int ct = 0; ct < 2; ++ct)
            acc[rt][ct] = (floatx4){0.f, 0.f, 0.f, 0.f};

    short8 bA[2][2], bB[2][2];                   // ping-pong B (32 VGPR total)

    // ---- prologue: B(kt=0) + DMA tile(kt=0) into buf 0 ----
    #pragma unroll
    for (int ct = 0; ct < 2; ++ct) {
        bA[ct][0] = bp[(size_t)((kt0 * 8 + ct0 + ct) * 2 + 0) * 64 + ln];
        bA[ct][1] = bp[(size_t)((kt0 * 8 + ct0 + ct) * 2 + 1) * 64 + ln];
    }
    __builtin_amdgcn_sched_barrier(0);
    dma16(gb, ldst0);
    __builtin_amdgcn_sched_barrier(0);
    __syncthreads();    // drains prologue DMA + B

    // one phase: issue B(kt+1)+DMA(kt+1) early, compute kt (no vmem), barrier
    #define PHASE(kt, BUF, bc, bn, LDSTN)                                      \
    {                                                                          \
        if ((kt) + 1 < 32) {                                                   \
            const int ktn = kt0 + (kt) + 1;                                    \
            _Pragma("unroll")                                                  \
            for (int ct = 0; ct < 2; ++ct) {                                   \
                bn[ct][0] = bp[(size_t)((ktn * 8 + ct0 + ct) * 2 + 0) * 64 + ln]; \
                bn[ct][1] = bp[(size_t)((ktn * 8 + ct0 + ct) * 2 + 1) * 64 + ln]; \
            }                                                                  \
            __builtin_amdgcn_sched_barrier(0);                                 \
            dma16(gb + ((kt) + 1) * 32, LDSTN);                                \
            __builtin_amdgcn_sched_barrier(0);                                 \
        }                                                                      \
        short8 ahi[2], alo[2];                                                 \
        {                                                                      \
            const float4 f0 = *(const float4*)&xb[BUF][kg][fb0 + p0 * 4];      \
            const float4 f1 = *(const float4*)&xb[BUF][kg][fb0 + p1 * 4];      \
            split8(f0, f1, &ahi[0], &alo[0]);                                  \
            const float4 g0 = *(const float4*)&xb[BUF][kg][fb1 + p0 * 4];      \
            const float4 g1 = *(const float4*)&xb[BUF][kg][fb1 + p1 * 4];      \
            split8(g0, g1, &ahi[1], &alo[1]);                                  \
        }                                                                      \
        _Pragma("unroll")                                                      \
        for (int ct = 0; ct < 2; ++ct) {                                       \
            const short8 bh = bc[ct][0];                                       \
            const short8 bl = bc[ct][1];                                       \
            acc[0][ct] = __builtin_amdgcn_mfma_f32_16x16x32_bf16(ahi[0], bh, acc[0][ct], 0, 0, 0); \
            acc[1][ct] = __builtin_amdgcn_mfma_f32_16x16x32_bf16(ahi[1], bh, acc[1][ct], 0, 0, 0); \
            acc[0][ct] = __builtin_amdgcn_mfma_f32_16x16x32_bf16(ahi[0], bl, acc[0][ct], 0, 0, 0); \
            acc[1][ct] = __builtin_amdgcn_mfma_f32_16x16x32_bf16(ahi[1], bl, acc[1][ct], 0, 0, 0); \
            acc[0][ct] = __builtin_amdgcn_mfma_f32_16x16x32_bf16(alo[0], bh, acc[0][ct], 0, 0, 0); \
            acc[1][ct] = __builtin_amdgcn_mfma_f32_16x16x32_bf16(alo[1], bh, acc[1][ct], 0, 0, 0); \
        }                                                                      \
        __syncthreads();                                                       \
    }

    #pragma unroll
    for (int m = 0; m < 16; ++m) {
        PHASE(2 * m,     0, bA, bB, ldst1)
        PHASE(2 * m + 1, 1, bB, bA, ldst0)
    }
    #undef PHASE

    // ---- phased partial reduce into ew (C/D: col=l15, row=quad*4+reg) ----
    #pragma unroll
    for (int p = 0; p < 2; ++p) {
        if (kg == p) {
            #pragma unroll
            for (int rt = 0; rt < 2; ++rt)
                #pragma unroll
                for (int r = 0; r < 4; ++r) {
                    const int row = rh + rt * 16 + quad * 4 + r;
                    #pragma unroll
                    for (int ct = 0; ct < 2; ++ct) {
                        const int col = (ct0 + ct) * 16 + l15;
                        if (p == 0) ew[row][col]  = acc[rt][ct][r];
                        else        ew[row][col] += acc[rt][ct][r];
                    }
                }
        }
        __syncthreads();
    }

    // ---- gate: 16 waves x 4 rows each ----
    int k = kptr[0];
    if (k < 1) k = 1;
    if (k > NEXP) k = NEXP;

    #pragma unroll
    for (int rr = 0; rr < 4; ++rr) {
        const int row  = wid * 4 + rr;
        const int grow = rowbase + row;
        const float clean = ew[row][ln];
        const float noisy = ew[row][NEXP + ln];
        const float nz    = noise[(size_t)grow * NEXP + ln];
        const float ewv   = clean + nz * softplus_f(noisy);
        float margin;
        const float val = row_gate(ln, ewv, k, &margin);
        out[(size_t)grow * NEXP + ln] = val;
        if (margin < TAU && ln == 0) {
            const int pos = atomicAdd(counter, 1);
            list[pos] = grow;
        }
    }
}

// ---------------- exact fp32 recheck for low-margin rows ----------------
__global__ __launch_bounds__(256) void recheck_kernel(
    const float* __restrict__ x,
    const float* __restrict__ gw,
    const float* __restrict__ nw,
    const float* __restrict__ noise,
    const int* __restrict__ kptr,
    float* __restrict__ out,
    const int* __restrict__ counter,
    const int* __restrict__ list)
{
    __shared__ float xr[DDIM];      // 8 KB
    __shared__ float parts[256];
    __shared__ float lg[NCOL];

    const int tid = threadIdx.x;
    const int cnt = counter[0];

    int k = kptr[0];
    if (k < 1) k = 1;
    if (k > NEXP) k = NEXP;

    for (int ii = blockIdx.x; ii < cnt; ii += gridDim.x) {
        const int row = list[ii];
        const float4* xs = (const float4*)(x + (size_t)row * DDIM);
        #pragma unroll
        for (int j = 0; j < 2; ++j)
            ((float4*)xr)[tid + j * 256] = xs[tid + j * 256];
        __syncthreads();

        const int e = tid & 127;
        const int half = tid >> 7;
        const float* wc = (e < NEXP) ? (gw + (size_t)e * DDIM)
                                     : (nw + (size_t)(e - NEXP) * DDIM);
        wc += half * 1024;
        const float* xc = xr + half * 1024;
        float s = 0.f;
        #pragma unroll 4
        for (int j = 0; j < 1024; j += 4) {
            float4 w4 = *(const float4*)&wc[j];
            s += xc[j] * w4.x + xc[j + 1] * w4.y + xc[j + 2] * w4.z + xc[j + 3] * w4.w;
        }
        parts[tid] = s;
        __syncthreads();
        if (tid < NCOL) lg[tid] = parts[tid] + parts[tid + 128];
        __syncthreads();
        if (tid < NEXP) {
            const float ew = lg[tid] + noise[(size_t)row * NEXP + tid] * softplus_f(lg[NEXP + tid]);
            float margin;
            const float val = row_gate(tid, ew, k, &margin);
            out[(size_t)row * NEXP + tid] = val;
        }
        __syncthreads();
    }
}

// ---------------- fallback: exact per-row (only if ws too small) ----------------
__global__ __launch_bounds__(256) void naive_kernel(
    const float* __restrict__ x,
    const float* __restrict__ gw,
    const float* __restrict__ nw,
    const float* __restrict__ noise,
    const int* __restrict__ kptr,
    float* __restrict__ out)
{
    const int lane = threadIdx.x & 63;
    const int wave = threadIdx.x >> 6;
    const int row  = blockIdx.x * 4 + wave;
    if (row >= NROWS) return;

    int k = kptr[0];
    if (k < 1) k = 1;
    if (k > NEXP) k = NEXP;

    const float* xr = x  + (size_t)row  * DDIM;
    const float* g  = gw + (size_t)lane * DDIM;
    const float* w2 = nw + (size_t)lane * DDIM;
    float c = 0.f, n = 0.f;
    for (int d = 0; d < DDIM; ++d) {
        const float xv = xr[d];
        c += xv * g[d];
        n += xv * w2[d];
    }
    const float ew = c + noise[(size_t)row * NEXP + lane] * softplus_f(n);
    float margin;
    out[(size_t)row * NEXP + lane] = row_gate(lane, ew, k, &margin);
}

// ---------------------------------------------------------------------------
extern "C" void kernel_launch(void* const* d_in, const int* in_sizes, int n_in,
                              void* d_out, int out_size, void* d_ws, size_t ws_size,
                              hipStream_t stream)
{
    const float* x     = (const float*)d_in[0];
    const float* gw    = (const float*)d_in[1];
    const float* nw    = (const float*)d_in[2];
    const float* noise = (const float*)d_in[3];
    const int*   kptr  = (const int*)d_in[4];
    float* out = (float*)d_out;

    // ws: bpk (1 MB) | counter (256 B) | list (64 KB)
    const size_t BPK_BYTES = (size_t)NCOL * DDIM * 2 * sizeof(unsigned short); // 1 MB
    const size_t TAIL      = 256 + NROWS * sizeof(int);

    if (ws_size < BPK_BYTES + TAIL) {
        hipLaunchKernelGGL(naive_kernel, dim3(NROWS / 4), dim3(256), 0, stream,
                           x, gw, nw, noise, kptr, out);
        return;
    }

    unsigned short* bpk     = (unsigned short*)d_ws;
    int*            counter = (int*)((char*)d_ws + BPK_BYTES);
    int*            list    = counter + 64;

    hipLaunchKernelGGL(wprep_kernel, dim3(128), dim3(256), 0, stream,
                       gw, nw, bpk, counter);
    hipLaunchKernelGGL(fusedE2_kernel, dim3(NROWS / 64), dim3(1024), 0, stream,
                       x, bpk, noise, kptr, out, counter, list);
    hipLaunchKernelGGL(recheck_kernel, dim3(256), dim3(256), 0, stream,
                       x, bpk ? (const float*)gw : gw, nw, noise, kptr, out, counter, list);
}